// Round 1
// baseline (1094.106 us; speedup 1.0000x reference)
//
#include <hip/hip_runtime.h>
#include <math.h>

#define NPIX (512*512)
#define NB 16
#define RAD 60
#define DSZ 120

// ---------------- device helpers ----------------

// torch/jax grid_sample semantics: bilinear, zero padding, align_corners=False
__device__ __forceinline__ float gs_bilinear(const float* img, int H, int W,
                                             float gx, float gy) {
    float x = ((gx + 1.0f) * (float)W - 1.0f) * 0.5f;
    float y = ((gy + 1.0f) * (float)H - 1.0f) * 0.5f;
    float xf = floorf(x), yf = floorf(y);
    int ix = (int)xf, iy = (int)yf;
    float wx = x - xf, wy = y - yf;
    float v = 0.0f;
    bool vx0 = (ix >= 0) && (ix < W);
    bool vx1 = (ix >= -1) && (ix < W - 1);
    bool vy0 = (iy >= 0) && (iy < H);
    bool vy1 = (iy >= -1) && (iy < H - 1);
    // tap order matches reference: (x0,y0), (x0+1,y0), (x0,y0+1), (x0+1,y0+1)
    if (vx0 && vy0) v += img[iy*W + ix]         * ((1.0f - wx) * (1.0f - wy));
    if (vx1 && vy0) v += img[iy*W + ix + 1]     * (wx * (1.0f - wy));
    if (vx0 && vy1) v += img[(iy+1)*W + ix]     * ((1.0f - wx) * wy);
    if (vx1 && vy1) v += img[(iy+1)*W + ix + 1] * (wx * wy);
    return v;
}

// ---------------- kernels ----------------

// invert [[a,b,tx],[c,d,ty],[0,0,1]] via no-pivot LU solve (|a| >> |c| for this data),
// mirroring jnp.linalg.inv's lu_solve structure in f32.
__global__ void k_prep(const float* __restrict__ sc, const float* __restrict__ rot,
                       const float* __restrict__ tr, float* __restrict__ ws_inv) {
    int t = blockIdx.x * blockDim.x + threadIdx.x;
    if (t >= 48) return;
    int m = t >> 4, b = t & 15;
    const float* th = (m == 0 ? sc : (m == 1 ? rot : tr)) + b * 6;
    float a  = th[0], bb = th[1], tx = th[2];
    float c  = th[3], d  = th[4], ty = th[5];
    float L10 = c / a;
    float dp  = d  - L10 * bb;   // d'
    float typ = ty - L10 * tx;   // ty'
    // column 0
    float i10 = (0.0f - L10) / dp;
    float i00 = (1.0f - bb * i10) / a;
    // column 1
    float i11 = 1.0f / dp;
    float i01 = (0.0f - bb * i11) / a;
    // column 2
    float i12 = (0.0f - typ) / dp;
    float i02 = (0.0f - bb * i12 - tx) / a;
    float* o = ws_inv + m * 96 + b * 6;
    o[0] = i00; o[1] = i01; o[2] = i02;
    o[3] = i10; o[4] = i11; o[5] = i12;
}

// jax.image.resize linear 128->512: s = (i+0.5)/4 - 0.5, edge renormalization == index clamp
__global__ void __launch_bounds__(256) k_upsample(const float* __restrict__ in,
                                                  float* __restrict__ out) {
    int b = blockIdx.y;
    int p = blockIdx.x * 256 + threadIdx.x;
    int y = p >> 9, x = p & 511;
    const float* src = in + b * 128 * 128;
    float sx = (float)x * 0.25f - 0.375f;
    float sy = (float)y * 0.25f - 0.375f;
    float fx0 = floorf(sx), fy0 = floorf(sy);
    int ix = (int)fx0, iy = (int)fy0;
    float fx = sx - fx0, fy = sy - fy0;
    int ix0 = min(max(ix, 0), 127),     ix1 = min(max(ix + 1, 0), 127);
    int iy0 = min(max(iy, 0), 127),     iy1 = min(max(iy + 1, 0), 127);
    float v00 = src[iy0 * 128 + ix0], v10 = src[iy0 * 128 + ix1];
    float v01 = src[iy1 * 128 + ix0], v11 = src[iy1 * 128 + ix1];
    float v = (v00 * (1.0f - fx) + v10 * fx) * (1.0f - fy)
            + (v01 * (1.0f - fx) + v11 * fx) * fy;
    out[(size_t)b * NPIX + p] = v;
}

// one affine grid_sample pass over (B,512,512)
__global__ void __launch_bounds__(256) k_gsample(const float* __restrict__ src,
                                                 float* __restrict__ dst,
                                                 const float* __restrict__ thetas) {
    int b = blockIdx.y;
    int p = blockIdx.x * 256 + threadIdx.x;
    int y = p >> 9, x = p & 511;
    const float* th = thetas + b * 6;
    float X = (2.0f * (float)x + 1.0f) / 512.0f - 1.0f;
    float Y = (2.0f * (float)y + 1.0f) / 512.0f - 1.0f;
    float gx = th[0] * X + th[1] * Y + th[2];
    float gy = th[3] * X + th[4] * Y + th[5];
    dst[(size_t)b * NPIX + p] = gs_bilinear(src + (size_t)b * NPIX, 512, 512, gx, gy);
}

__device__ __forceinline__ float rm2_val(const float* mk, const float* t2, int cx_, int ry_) {
    float X2 = (2.0f * (float)cx_ + 1.0f) / 512.0f - 1.0f;
    float Y2 = (2.0f * (float)ry_ + 1.0f) / 512.0f - 1.0f;
    float g2x = t2[0] * X2 + t2[1] * Y2 + t2[2];
    float g2y = t2[3] * X2 + t2[4] * Y2 + t2[5];
    return gs_bilinear(mk, 512, 512, g2x, g2y);
}

// fused: rm = gs(gs(mask_j, g2), g1) >= 0.5; grid.y = j*16+b
__global__ void __launch_bounds__(256) k_mask_chain(const float* __restrict__ masks,
                                                    float* __restrict__ out3,
                                                    const float* __restrict__ inv1,
                                                    const float* __restrict__ inv2) {
    int jb = blockIdx.y;
    int j = jb >> 4, b = jb & 15;
    int p = blockIdx.x * 256 + threadIdx.x;
    int y = p >> 9, x = p & 511;
    const float* t1 = inv1 + b * 6;
    const float* t2 = inv2 + b * 6;
    const float* mk = masks + (size_t)j * NPIX;
    float X = (2.0f * (float)x + 1.0f) / 512.0f - 1.0f;
    float Y = (2.0f * (float)y + 1.0f) / 512.0f - 1.0f;
    float gx = t1[0] * X + t1[1] * Y + t1[2];
    float gy = t1[3] * X + t1[4] * Y + t1[5];
    float sx = ((gx + 1.0f) * 512.0f - 1.0f) * 0.5f;
    float sy = ((gy + 1.0f) * 512.0f - 1.0f) * 0.5f;
    float xf = floorf(sx), yf = floorf(sy);
    int ix = (int)xf, iy = (int)yf;
    float wx = sx - xf, wy = sy - yf;
    float v = 0.0f;
    bool vx0 = (ix >= 0) && (ix < 512);
    bool vx1 = (ix >= -1) && (ix < 511);
    bool vy0 = (iy >= 0) && (iy < 512);
    bool vy1 = (iy >= -1) && (iy < 511);
    if (vx0 && vy0) v += rm2_val(mk, t2, ix,     iy    ) * ((1.0f - wx) * (1.0f - wy));
    if (vx1 && vy0) v += rm2_val(mk, t2, ix + 1, iy    ) * (wx * (1.0f - wy));
    if (vx0 && vy1) v += rm2_val(mk, t2, ix,     iy + 1) * ((1.0f - wx) * wy);
    if (vx1 && vy1) v += rm2_val(mk, t2, ix + 1, iy + 1) * (wx * wy);
    out3[(size_t)jb * NPIX + p] = (v >= 0.5f) ? 1.0f : 0.0f;
}

// COM pass 1: per (j,b) -> sum(mask), sum(pred*mask)   [f64 accumulation]
__global__ void __launch_bounds__(256) k_stats1(const float* __restrict__ pred,
                                                const float* __restrict__ mrot,
                                                double* __restrict__ statsd) {
    int jb = blockIdx.x;
    int b = jb & 15;
    const float* img = pred + (size_t)b * NPIX;
    const float* mk  = mrot + (size_t)jb * NPIX;
    double msum = 0.0, isum = 0.0;
    for (int p = threadIdx.x; p < NPIX; p += 256) {
        float m = mk[p];
        if (m != 0.0f) {
            msum += (double)m;
            isum += (double)(img[p] * m);
        }
    }
    for (int o = 32; o > 0; o >>= 1) {
        msum += __shfl_down(msum, o, 64);
        isum += __shfl_down(isum, o, 64);
    }
    __shared__ double s0[4], s1[4];
    int lane = threadIdx.x & 63, w = threadIdx.x >> 6;
    if (lane == 0) { s0[w] = msum; s1[w] = isum; }
    __syncthreads();
    if (threadIdx.x == 0) {
        double M = s0[0] + s0[1] + s0[2] + s0[3];
        double I = s1[0] + s1[1] + s1[2] + s1[3];
        statsd[jb * 6 + 0] = M;
        statsd[jb * 6 + 1] = I;
    }
}

// COM pass 2: threshold, weighted centroid, crop origin (clamped like dynamic_slice)
__global__ void __launch_bounds__(256) k_stats2(const float* __restrict__ pred,
                                                const float* __restrict__ mrot,
                                                const double* __restrict__ statsd,
                                                int* __restrict__ xy) {
    int jb = blockIdx.x;
    int b = jb & 15;
    double msum = statsd[jb * 6 + 0];
    double isum = statsd[jb * 6 + 1];
    double thr = (isum / fmax(msum, 1.0)) * 1.5;
    const float* img = pred + (size_t)b * NPIX;
    const float* mk  = mrot + (size_t)jb * NPIX;
    double wsum = 0.0, sy = 0.0, sx = 0.0;
    for (int p = threadIdx.x; p < NPIX; p += 256) {
        float m = mk[p];
        if (m != 0.0f) {
            float v = img[p] * m;
            if ((double)v > thr) {
                double vd = (double)v;
                wsum += vd;
                sy += vd * (double)(p >> 9);   // row  (cx in reference)
                sx += vd * (double)(p & 511);  // col  (cy in reference)
            }
        }
    }
    for (int o = 32; o > 0; o >>= 1) {
        wsum += __shfl_down(wsum, o, 64);
        sy   += __shfl_down(sy,   o, 64);
        sx   += __shfl_down(sx,   o, 64);
    }
    __shared__ double s0[4], s1[4], s2[4];
    int lane = threadIdx.x & 63, w = threadIdx.x >> 6;
    if (lane == 0) { s0[w] = wsum; s1[w] = sy; s2[w] = sx; }
    __syncthreads();
    if (threadIdx.x == 0) {
        double W = s0[0] + s0[1] + s0[2] + s0[3];
        double SY = s1[0] + s1[1] + s1[2] + s1[3];
        double SX = s2[0] + s2[1] + s2[2] + s2[3];
        double tot = W + 1e-8;
        double cx = SY / tot;   // row centroid
        double cy = SX / tot;   // col centroid
        int x0 = (int)rint(cx) - RAD;
        int y0 = (int)rint(cy) - RAD;
        x0 = min(max(x0, 0), 512 - DSZ);
        y0 = min(max(y0, 0), 512 - DSZ);
        xy[jb * 2 + 0] = x0;
        xy[jb * 2 + 1] = y0;
    }
}

// revise one mask index j across the batch: crop->dot divide->grid_sample->write back
__global__ void __launch_bounds__(256) k_patch(float* __restrict__ img,
                                               const int* __restrict__ xy,
                                               const float* __restrict__ inv1,
                                               const float* __restrict__ adj, int j) {
    __shared__ float patch[DSZ * DSZ];
    int b = blockIdx.x;
    int jb = j * 16 + b;
    int x0 = xy[jb * 2 + 0];   // row start
    int y0 = xy[jb * 2 + 1];   // col start
    float a = adj[b];
    float* im = img + (size_t)b * NPIX;
    // phase 1: load patch (with dot-circle division) into LDS
    for (int t = threadIdx.x; t < DSZ * DSZ; t += 256) {
        int u = t / DSZ, v = t % DSZ;
        float val = im[(x0 + u) * 512 + (y0 + v)];
        int du = u - RAD, dv = v - RAD;
        if (du * du + dv * dv <= 16) val = val / a;
        patch[t] = val;
    }
    __syncthreads();
    // phase 2: grid-sample the patch with inv scaler_shear theta, write back in place
    const float* th = inv1 + b * 6;
    float t0 = th[0], t1 = th[1], t2 = th[2], t3 = th[3], t4 = th[4], t5 = th[5];
    for (int t = threadIdx.x; t < DSZ * DSZ; t += 256) {
        int py = t / DSZ, px = t % DSZ;
        float X = (2.0f * (float)px + 1.0f) / 120.0f - 1.0f;
        float Y = (2.0f * (float)py + 1.0f) / 120.0f - 1.0f;
        float gx = t0 * X + t1 * Y + t2;
        float gy = t3 * X + t4 * Y + t5;
        float o = gs_bilinear(patch, DSZ, DSZ, gx, gy);
        im[(x0 + py) * 512 + (y0 + px)] = o;
    }
}

// ---------------- launcher ----------------

extern "C" void kernel_launch(void* const* d_in, const int* in_sizes, int n_in,
                              void* d_out, int out_size, void* d_ws, size_t ws_size,
                              hipStream_t stream) {
    const float* base  = (const float*)d_in[0];   // (16,1,128,128)
    const float* sc    = (const float*)d_in[1];   // (16,2,3)
    const float* rot   = (const float*)d_in[2];   // (16,2,3)
    const float* tr    = (const float*)d_in[3];   // (16,2,3)
    const float* adj   = (const float*)d_in[4];   // (16,)
    const float* masks = (const float*)d_in[5];   // (4,512,512)

    float* out  = (float*)d_out;
    float* out0 = out;                               // base_inp
    float* out1 = out0 + (size_t)NB * NPIX;          // pred_input
    float* out2 = out1 + (size_t)NB * NPIX;          // pred_revise
    float* out3 = out2 + (size_t)NB * NPIX;          // masks_rot (4,16,512,512)

    float*  wsf    = (float*)d_ws;
    float*  inv1   = wsf;          // scaler_shear^-1
    float*  inv2   = wsf + 96;     // rotation^-1
    float*  inv3   = wsf + 192;    // translation^-1
    double* statsd = (double*)((char*)d_ws + 2048);
    int*    xy     = (int*)((char*)d_ws + 8192);

    dim3 gridImg(NPIX / 256, NB);

    k_prep<<<1, 64, 0, stream>>>(sc, rot, tr, wsf);
    k_upsample<<<gridImg, 256, 0, stream>>>(base, out0);

    // image chain: base_inp -g3-> tmpA(out2) -g2-> tmpB(out3[:16]) -g1-> pred_input(out1)
    k_gsample<<<gridImg, 256, 0, stream>>>(out0, out2, inv3);
    k_gsample<<<gridImg, 256, 0, stream>>>(out2, out3, inv2);
    k_gsample<<<gridImg, 256, 0, stream>>>(out3, out1, inv1);

    // masks (overwrites the tmp regions with final data)
    k_mask_chain<<<dim3(NPIX / 256, 64), 256, 0, stream>>>(masks, out3, inv1, inv2);

    // pred_revise starts as a copy of pred_input
    hipMemcpyAsync(out2, out1, (size_t)NB * NPIX * sizeof(float),
                   hipMemcpyDeviceToDevice, stream);

    k_stats1<<<64, 256, 0, stream>>>(out1, out3, statsd);
    k_stats2<<<64, 256, 0, stream>>>(out1, out3, statsd, xy);

    // sequential over j: matches reference update order (patches may overlap across j)
    for (int j = 0; j < 4; ++j)
        k_patch<<<NB, 256, 0, stream>>>(out2, xy, inv1, adj, j);
}

// Round 2
// 497.878 us; speedup vs baseline: 2.1975x; 2.1975x over previous
//
#include <hip/hip_runtime.h>
#include <math.h>

#define NPIX (512*512)
#define NB 16
#define RAD 60
#define DSZ 120
#define NCHUNK 32
#define CHPIX (NPIX / NCHUNK)

// ---------------- device helpers ----------------

// torch/jax grid_sample semantics: bilinear, zero padding, align_corners=False
__device__ __forceinline__ float gs_bilinear(const float* img, int H, int W,
                                             float gx, float gy) {
    float x = ((gx + 1.0f) * (float)W - 1.0f) * 0.5f;
    float y = ((gy + 1.0f) * (float)H - 1.0f) * 0.5f;
    float xf = floorf(x), yf = floorf(y);
    int ix = (int)xf, iy = (int)yf;
    float wx = x - xf, wy = y - yf;
    float v = 0.0f;
    bool vx0 = (ix >= 0) && (ix < W);
    bool vx1 = (ix >= -1) && (ix < W - 1);
    bool vy0 = (iy >= 0) && (iy < H);
    bool vy1 = (iy >= -1) && (iy < H - 1);
    if (vx0 && vy0) v += img[iy*W + ix]         * ((1.0f - wx) * (1.0f - wy));
    if (vx1 && vy0) v += img[iy*W + ix + 1]     * (wx * (1.0f - wy));
    if (vx0 && vy1) v += img[(iy+1)*W + ix]     * ((1.0f - wx) * wy);
    if (vx1 && vy1) v += img[(iy+1)*W + ix + 1] * (wx * wy);
    return v;
}

// ---------------- kernels ----------------

// invert [[a,b,tx],[c,d,ty],[0,0,1]] via no-pivot LU solve (|a| >> |c| for this data)
__global__ void k_prep(const float* __restrict__ sc, const float* __restrict__ rot,
                       const float* __restrict__ tr, float* __restrict__ ws_inv) {
    int t = blockIdx.x * blockDim.x + threadIdx.x;
    if (t >= 48) return;
    int m = t >> 4, b = t & 15;
    const float* th = (m == 0 ? sc : (m == 1 ? rot : tr)) + b * 6;
    float a  = th[0], bb = th[1], tx = th[2];
    float c  = th[3], d  = th[4], ty = th[5];
    float L10 = c / a;
    float dp  = d  - L10 * bb;
    float typ = ty - L10 * tx;
    float i10 = (0.0f - L10) / dp;
    float i00 = (1.0f - bb * i10) / a;
    float i11 = 1.0f / dp;
    float i01 = (0.0f - bb * i11) / a;
    float i12 = (0.0f - typ) / dp;
    float i02 = (0.0f - bb * i12 - tx) / a;
    float* o = ws_inv + m * 96 + b * 6;
    o[0] = i00; o[1] = i01; o[2] = i02;
    o[3] = i10; o[4] = i11; o[5] = i12;
}

// jax.image.resize linear 128->512
__global__ void __launch_bounds__(256) k_upsample(const float* __restrict__ in,
                                                  float* __restrict__ out) {
    int b = blockIdx.y;
    int p = blockIdx.x * 256 + threadIdx.x;
    int y = p >> 9, x = p & 511;
    const float* src = in + b * 128 * 128;
    float sx = (float)x * 0.25f - 0.375f;
    float sy = (float)y * 0.25f - 0.375f;
    float fx0 = floorf(sx), fy0 = floorf(sy);
    int ix = (int)fx0, iy = (int)fy0;
    float fx = sx - fx0, fy = sy - fy0;
    int ix0 = min(max(ix, 0), 127),     ix1 = min(max(ix + 1, 0), 127);
    int iy0 = min(max(iy, 0), 127),     iy1 = min(max(iy + 1, 0), 127);
    float v00 = src[iy0 * 128 + ix0], v10 = src[iy0 * 128 + ix1];
    float v01 = src[iy1 * 128 + ix0], v11 = src[iy1 * 128 + ix1];
    float v = (v00 * (1.0f - fx) + v10 * fx) * (1.0f - fy)
            + (v01 * (1.0f - fx) + v11 * fx) * fy;
    out[(size_t)b * NPIX + p] = v;
}

// one affine grid_sample pass over (B,512,512); optional dual store
__global__ void __launch_bounds__(256) k_gsample(const float* __restrict__ src,
                                                 float* __restrict__ dst,
                                                 float* __restrict__ dst2,
                                                 const float* __restrict__ thetas) {
    int b = blockIdx.y;
    int p = blockIdx.x * 256 + threadIdx.x;
    int y = p >> 9, x = p & 511;
    const float* th = thetas + b * 6;
    float X = (2.0f * (float)x + 1.0f) / 512.0f - 1.0f;
    float Y = (2.0f * (float)y + 1.0f) / 512.0f - 1.0f;
    float gx = th[0] * X + th[1] * Y + th[2];
    float gy = th[3] * X + th[4] * Y + th[5];
    float v = gs_bilinear(src + (size_t)b * NPIX, 512, 512, gx, gy);
    dst[(size_t)b * NPIX + p] = v;
    if (dst2) dst2[(size_t)b * NPIX + p] = v;
}

__device__ __forceinline__ float rm2_val(const float* mk, const float* t2, int cx_, int ry_) {
    float X2 = (2.0f * (float)cx_ + 1.0f) / 512.0f - 1.0f;
    float Y2 = (2.0f * (float)ry_ + 1.0f) / 512.0f - 1.0f;
    float g2x = t2[0] * X2 + t2[1] * Y2 + t2[2];
    float g2y = t2[3] * X2 + t2[4] * Y2 + t2[5];
    return gs_bilinear(mk, 512, 512, g2x, g2y);
}

// fused: rm = gs(gs(mask_j, g2), g1) >= 0.5; grid.y = j*16+b
__global__ void __launch_bounds__(256) k_mask_chain(const float* __restrict__ masks,
                                                    float* __restrict__ out3,
                                                    const float* __restrict__ inv1,
                                                    const float* __restrict__ inv2) {
    int jb = blockIdx.y;
    int j = jb >> 4, b = jb & 15;
    int p = blockIdx.x * 256 + threadIdx.x;
    int y = p >> 9, x = p & 511;
    const float* t1 = inv1 + b * 6;
    const float* t2 = inv2 + b * 6;
    const float* mk = masks + (size_t)j * NPIX;
    float X = (2.0f * (float)x + 1.0f) / 512.0f - 1.0f;
    float Y = (2.0f * (float)y + 1.0f) / 512.0f - 1.0f;
    float gx = t1[0] * X + t1[1] * Y + t1[2];
    float gy = t1[3] * X + t1[4] * Y + t1[5];
    float sx = ((gx + 1.0f) * 512.0f - 1.0f) * 0.5f;
    float sy = ((gy + 1.0f) * 512.0f - 1.0f) * 0.5f;
    float xf = floorf(sx), yf = floorf(sy);
    int ix = (int)xf, iy = (int)yf;
    float wx = sx - xf, wy = sy - yf;
    float v = 0.0f;
    bool vx0 = (ix >= 0) && (ix < 512);
    bool vx1 = (ix >= -1) && (ix < 511);
    bool vy0 = (iy >= 0) && (iy < 512);
    bool vy1 = (iy >= -1) && (iy < 511);
    if (vx0 && vy0) v += rm2_val(mk, t2, ix,     iy    ) * ((1.0f - wx) * (1.0f - wy));
    if (vx1 && vy0) v += rm2_val(mk, t2, ix + 1, iy    ) * (wx * (1.0f - wy));
    if (vx0 && vy1) v += rm2_val(mk, t2, ix,     iy + 1) * ((1.0f - wx) * wy);
    if (vx1 && vy1) v += rm2_val(mk, t2, ix + 1, iy + 1) * (wx * wy);
    out3[(size_t)jb * NPIX + p] = (v >= 0.5f) ? 1.0f : 0.0f;
}

// COM pass 1 (chunked): per (jb, chunk) partial sum(mask), sum(pred*mask) [f64]
__global__ void __launch_bounds__(256) k_stats1(const float* __restrict__ pred,
                                                const float* __restrict__ mrot,
                                                double* __restrict__ part1) {
    int jb = blockIdx.y;
    int b = jb & 15;
    const float* img = pred + (size_t)b * NPIX;
    const float* mk  = mrot + (size_t)jb * NPIX;
    int base = blockIdx.x * CHPIX;
    double msum = 0.0, isum = 0.0;
    for (int i = threadIdx.x; i < CHPIX; i += 256) {
        int p = base + i;
        float m = mk[p];
        if (m != 0.0f) {
            msum += (double)m;
            isum += (double)(img[p] * m);
        }
    }
    for (int o = 32; o > 0; o >>= 1) {
        msum += __shfl_down(msum, o, 64);
        isum += __shfl_down(isum, o, 64);
    }
    __shared__ double s0[4], s1[4];
    int lane = threadIdx.x & 63, w = threadIdx.x >> 6;
    if (lane == 0) { s0[w] = msum; s1[w] = isum; }
    __syncthreads();
    if (threadIdx.x == 0) {
        double M = s0[0] + s0[1] + s0[2] + s0[3];
        double I = s1[0] + s1[1] + s1[2] + s1[3];
        part1[(jb * NCHUNK + blockIdx.x) * 2 + 0] = M;
        part1[(jb * NCHUNK + blockIdx.x) * 2 + 1] = I;
    }
}

// combine pass-1 partials in fixed order -> threshold per jb
__global__ void k_comb1(const double* __restrict__ part1, double* __restrict__ thr) {
    int jb = blockIdx.x * blockDim.x + threadIdx.x;
    if (jb >= 64) return;
    double M = 0.0, I = 0.0;
    for (int c = 0; c < NCHUNK; ++c) {
        M += part1[(jb * NCHUNK + c) * 2 + 0];
        I += part1[(jb * NCHUNK + c) * 2 + 1];
    }
    thr[jb] = (I / fmax(M, 1.0)) * 1.5;
}

// COM pass 2 (chunked): thresholded weighted centroid partials [f64]
__global__ void __launch_bounds__(256) k_stats2(const float* __restrict__ pred,
                                                const float* __restrict__ mrot,
                                                const double* __restrict__ thr,
                                                double* __restrict__ part2) {
    int jb = blockIdx.y;
    int b = jb & 15;
    double t = thr[jb];
    const float* img = pred + (size_t)b * NPIX;
    const float* mk  = mrot + (size_t)jb * NPIX;
    int base = blockIdx.x * CHPIX;
    double wsum = 0.0, sy = 0.0, sx = 0.0;
    for (int i = threadIdx.x; i < CHPIX; i += 256) {
        int p = base + i;
        float m = mk[p];
        if (m != 0.0f) {
            float v = img[p] * m;
            if ((double)v > t) {
                double vd = (double)v;
                wsum += vd;
                sy += vd * (double)(p >> 9);   // row  (cx in reference)
                sx += vd * (double)(p & 511);  // col  (cy in reference)
            }
        }
    }
    for (int o = 32; o > 0; o >>= 1) {
        wsum += __shfl_down(wsum, o, 64);
        sy   += __shfl_down(sy,   o, 64);
        sx   += __shfl_down(sx,   o, 64);
    }
    __shared__ double s0[4], s1[4], s2[4];
    int lane = threadIdx.x & 63, w = threadIdx.x >> 6;
    if (lane == 0) { s0[w] = wsum; s1[w] = sy; s2[w] = sx; }
    __syncthreads();
    if (threadIdx.x == 0) {
        part2[(jb * NCHUNK + blockIdx.x) * 3 + 0] = s0[0] + s0[1] + s0[2] + s0[3];
        part2[(jb * NCHUNK + blockIdx.x) * 3 + 1] = s1[0] + s1[1] + s1[2] + s1[3];
        part2[(jb * NCHUNK + blockIdx.x) * 3 + 2] = s2[0] + s2[1] + s2[2] + s2[3];
    }
}

// combine pass-2 partials -> crop origins (clamped like dynamic_slice)
__global__ void k_comb2(const double* __restrict__ part2, int* __restrict__ xy) {
    int jb = blockIdx.x * blockDim.x + threadIdx.x;
    if (jb >= 64) return;
    double W = 0.0, SY = 0.0, SX = 0.0;
    for (int c = 0; c < NCHUNK; ++c) {
        W  += part2[(jb * NCHUNK + c) * 3 + 0];
        SY += part2[(jb * NCHUNK + c) * 3 + 1];
        SX += part2[(jb * NCHUNK + c) * 3 + 2];
    }
    double tot = W + 1e-8;
    int x0 = (int)rint(SY / tot) - RAD;
    int y0 = (int)rint(SX / tot) - RAD;
    x0 = min(max(x0, 0), 512 - DSZ);
    y0 = min(max(y0, 0), 512 - DSZ);
    xy[jb * 2 + 0] = x0;
    xy[jb * 2 + 1] = y0;
}

// revise one mask index j across the batch: crop->dot divide->grid_sample->write back
__global__ void __launch_bounds__(256) k_patch(float* __restrict__ img,
                                               const int* __restrict__ xy,
                                               const float* __restrict__ inv1,
                                               const float* __restrict__ adj, int j) {
    __shared__ float patch[DSZ * DSZ];
    int b = blockIdx.x;
    int jb = j * 16 + b;
    int x0 = xy[jb * 2 + 0];   // row start
    int y0 = xy[jb * 2 + 1];   // col start
    float a = adj[b];
    float* im = img + (size_t)b * NPIX;
    for (int t = threadIdx.x; t < DSZ * DSZ; t += 256) {
        int u = t / DSZ, v = t % DSZ;
        float val = im[(x0 + u) * 512 + (y0 + v)];
        int du = u - RAD, dv = v - RAD;
        if (du * du + dv * dv <= 16) val = val / a;
        patch[t] = val;
    }
    __syncthreads();
    const float* th = inv1 + b * 6;
    float t0 = th[0], t1 = th[1], t2 = th[2], t3 = th[3], t4 = th[4], t5 = th[5];
    for (int t = threadIdx.x; t < DSZ * DSZ; t += 256) {
        int py = t / DSZ, px = t % DSZ;
        float X = (2.0f * (float)px + 1.0f) / 120.0f - 1.0f;
        float Y = (2.0f * (float)py + 1.0f) / 120.0f - 1.0f;
        float gx = t0 * X + t1 * Y + t2;
        float gy = t3 * X + t4 * Y + t5;
        float o = gs_bilinear(patch, DSZ, DSZ, gx, gy);
        im[(x0 + py) * 512 + (y0 + px)] = o;
    }
}

// ---------------- launcher ----------------

extern "C" void kernel_launch(void* const* d_in, const int* in_sizes, int n_in,
                              void* d_out, int out_size, void* d_ws, size_t ws_size,
                              hipStream_t stream) {
    const float* base  = (const float*)d_in[0];
    const float* sc    = (const float*)d_in[1];
    const float* rot   = (const float*)d_in[2];
    const float* tr    = (const float*)d_in[3];
    const float* adj   = (const float*)d_in[4];
    const float* masks = (const float*)d_in[5];

    float* out  = (float*)d_out;
    float* out0 = out;                               // base_inp
    float* out1 = out0 + (size_t)NB * NPIX;          // pred_input
    float* out2 = out1 + (size_t)NB * NPIX;          // pred_revise
    float* out3 = out2 + (size_t)NB * NPIX;          // masks_rot (4,16,512,512)

    // ws layout (all offsets in bytes)
    float*  inv1  = (float*)d_ws;                    // 3*96 floats
    float*  inv2  = inv1 + 96;
    float*  inv3  = inv1 + 192;
    double* thr   = (double*)((char*)d_ws + 2048);           // 64 doubles
    double* part1 = (double*)((char*)d_ws + 4096);           // 64*32*2 doubles = 32 KB
    double* part2 = (double*)((char*)d_ws + 4096 + 33280);   // 64*32*3 doubles = 48 KB
    int*    xy    = (int*)((char*)d_ws + 4096 + 33280 + 49664); // 128 ints

    dim3 gridImg(NPIX / 256, NB);

    k_prep<<<1, 64, 0, stream>>>(sc, rot, tr, (float*)d_ws);
    k_upsample<<<gridImg, 256, 0, stream>>>(base, out0);

    // image chain: base_inp -g3-> tmpA(out2) -g2-> tmpB(out3[:16]) -g1-> out1 (+out2 copy)
    k_gsample<<<gridImg, 256, 0, stream>>>(out0, out2, nullptr, inv3);
    k_gsample<<<gridImg, 256, 0, stream>>>(out2, out3, nullptr, inv2);
    k_gsample<<<gridImg, 256, 0, stream>>>(out3, out1, out2, inv1);  // dual store

    // masks (overwrites the tmp regions with final data)
    k_mask_chain<<<dim3(NPIX / 256, 64), 256, 0, stream>>>(masks, out3, inv1, inv2);

    // COM stats, chunked two-level deterministic reduction
    dim3 gridStats(NCHUNK, 64);
    k_stats1<<<gridStats, 256, 0, stream>>>(out1, out3, part1);
    k_comb1<<<1, 64, 0, stream>>>(part1, thr);
    k_stats2<<<gridStats, 256, 0, stream>>>(out1, out3, thr, part2);
    k_comb2<<<1, 64, 0, stream>>>(part2, xy);

    // sequential over j: matches reference update order (patches may overlap across j)
    for (int j = 0; j < 4; ++j)
        k_patch<<<NB, 256, 0, stream>>>(out2, xy, inv1, adj, j);
}

// Round 3
// 418.127 us; speedup vs baseline: 2.6167x; 1.1907x over previous
//
#include <hip/hip_runtime.h>
#include <math.h>
#include <limits.h>

#define NPIX (512*512)
#define NB 16
#define RAD 60
#define DSZ 120

// ---------------- device helpers ----------------

// torch/jax grid_sample semantics: bilinear, zero padding, align_corners=False
__device__ __forceinline__ float gs_bilinear(const float* img, int H, int W,
                                             float gx, float gy) {
    float x = ((gx + 1.0f) * (float)W - 1.0f) * 0.5f;
    float y = ((gy + 1.0f) * (float)H - 1.0f) * 0.5f;
    float xf = floorf(x), yf = floorf(y);
    int ix = (int)xf, iy = (int)yf;
    float wx = x - xf, wy = y - yf;
    float v = 0.0f;
    bool vx0 = (ix >= 0) && (ix < W);
    bool vx1 = (ix >= -1) && (ix < W - 1);
    bool vy0 = (iy >= 0) && (iy < H);
    bool vy1 = (iy >= -1) && (iy < H - 1);
    if (vx0 && vy0) v += img[iy*W + ix]         * ((1.0f - wx) * (1.0f - wy));
    if (vx1 && vy0) v += img[iy*W + ix + 1]     * (wx * (1.0f - wy));
    if (vx0 && vy1) v += img[(iy+1)*W + ix]     * ((1.0f - wx) * wy);
    if (vx1 && vy1) v += img[(iy+1)*W + ix + 1] * (wx * wy);
    return v;
}

// ---------------- kernels ----------------

// inverses + per-call ws init (bbox sentinels, occupancy bitmap zeros)
__global__ void k_prep(const float* __restrict__ sc, const float* __restrict__ rot,
                       const float* __restrict__ tr, float* __restrict__ ws_inv,
                       int* __restrict__ bbox, unsigned* __restrict__ occ) {
    int t = threadIdx.x;
    if (t < 48) {
        int m = t >> 4, b = t & 15;
        const float* th = (m == 0 ? sc : (m == 1 ? rot : tr)) + b * 6;
        float a  = th[0], bb = th[1], tx = th[2];
        float c  = th[3], d  = th[4], ty = th[5];
        float L10 = c / a;
        float dp  = d  - L10 * bb;
        float typ = ty - L10 * tx;
        float i10 = (0.0f - L10) / dp;
        float i00 = (1.0f - bb * i10) / a;
        float i11 = 1.0f / dp;
        float i01 = (0.0f - bb * i11) / a;
        float i12 = (0.0f - typ) / dp;
        float i02 = (0.0f - bb * i12 - tx) / a;
        float* o = ws_inv + m * 96 + b * 6;
        o[0] = i00; o[1] = i01; o[2] = i02;
        o[3] = i10; o[4] = i11; o[5] = i12;
    }
    // bbox[jb*4 + {0:rmin,1:cmin,2:rmax,3:cmax}]
    bbox[t] = ((t & 3) < 2) ? INT_MAX : INT_MIN;
    if (t < 128) occ[t] = 0u;
}

// coarse occupancy: 1 bit per 16x16 tile per mask (32x32 tiles -> word=tilerow, bit=tilecol)
__global__ void k_occ(const float* __restrict__ masks, unsigned* __restrict__ occ) {
    int tile = blockIdx.x;          // 0..4095
    int j = tile >> 10, t = tile & 1023;
    int ty = t >> 5, tx = t & 31;
    const float* mk = masks + (size_t)j * NPIX;
    int any = 0;
    for (int i = threadIdx.x; i < 256; i += 64) {
        int py = ty * 16 + (i >> 4), px = tx * 16 + (i & 15);
        if (mk[py * 512 + px] != 0.0f) any = 1;
    }
    unsigned long long m = __ballot(any);
    if (threadIdx.x == 0 && m) atomicOr(&occ[j * 32 + ty], 1u << tx);
}

// jax.image.resize linear 128->512
__global__ void __launch_bounds__(256) k_upsample(const float* __restrict__ in,
                                                  float* __restrict__ out) {
    int b = blockIdx.y;
    int p = blockIdx.x * 256 + threadIdx.x;
    int y = p >> 9, x = p & 511;
    const float* src = in + b * 128 * 128;
    float sx = (float)x * 0.25f - 0.375f;
    float sy = (float)y * 0.25f - 0.375f;
    float fx0 = floorf(sx), fy0 = floorf(sy);
    int ix = (int)fx0, iy = (int)fy0;
    float fx = sx - fx0, fy = sy - fy0;
    int ix0 = min(max(ix, 0), 127),     ix1 = min(max(ix + 1, 0), 127);
    int iy0 = min(max(iy, 0), 127),     iy1 = min(max(iy + 1, 0), 127);
    float v00 = src[iy0 * 128 + ix0], v10 = src[iy0 * 128 + ix1];
    float v01 = src[iy1 * 128 + ix0], v11 = src[iy1 * 128 + ix1];
    float v = (v00 * (1.0f - fx) + v10 * fx) * (1.0f - fy)
            + (v01 * (1.0f - fx) + v11 * fx) * fy;
    out[(size_t)b * NPIX + p] = v;
}

// one affine grid_sample pass over (B,512,512); optional dual store
__global__ void __launch_bounds__(256) k_gsample(const float* __restrict__ src,
                                                 float* __restrict__ dst,
                                                 float* __restrict__ dst2,
                                                 const float* __restrict__ thetas) {
    int b = blockIdx.y;
    int p = blockIdx.x * 256 + threadIdx.x;
    int y = p >> 9, x = p & 511;
    const float* th = thetas + b * 6;
    float X = (2.0f * (float)x + 1.0f) / 512.0f - 1.0f;
    float Y = (2.0f * (float)y + 1.0f) / 512.0f - 1.0f;
    float gx = th[0] * X + th[1] * Y + th[2];
    float gy = th[3] * X + th[4] * Y + th[5];
    float v = gs_bilinear(src + (size_t)b * NPIX, 512, 512, gx, gy);
    dst[(size_t)b * NPIX + p] = v;
    if (dst2) dst2[(size_t)b * NPIX + p] = v;
}

__device__ __forceinline__ float rm2_val(const float* mk, const float* t2, int cx_, int ry_) {
    float X2 = (2.0f * (float)cx_ + 1.0f) / 512.0f - 1.0f;
    float Y2 = (2.0f * (float)ry_ + 1.0f) / 512.0f - 1.0f;
    float g2x = t2[0] * X2 + t2[1] * Y2 + t2[2];
    float g2y = t2[3] * X2 + t2[4] * Y2 + t2[5];
    return gs_bilinear(mk, 512, 512, g2x, g2y);
}

// fused: rm = gs(gs(mask_j, g2), g1) >= 0.5, with coarse-occupancy skip + set-pixel bbox
__global__ void __launch_bounds__(256) k_mask_chain(const float* __restrict__ masks,
                                                    float* __restrict__ out3,
                                                    const float* __restrict__ inv1,
                                                    const float* __restrict__ inv2,
                                                    const unsigned* __restrict__ occ,
                                                    int* __restrict__ bbox) {
    __shared__ unsigned socc[32];
    __shared__ int sbb[4];   // rmin, cmin, rmax, cmax (block-local)
    int jb = blockIdx.y;
    int j = jb >> 4, b = jb & 15;
    if (threadIdx.x < 32) socc[threadIdx.x] = occ[j * 32 + threadIdx.x];
    if (threadIdx.x == 0) { sbb[0] = INT_MAX; sbb[1] = INT_MAX; sbb[2] = INT_MIN; sbb[3] = INT_MIN; }
    __syncthreads();

    int p = blockIdx.x * 256 + threadIdx.x;
    int y = p >> 9, x = p & 511;
    const float* t1 = inv1 + b * 6;
    const float* t2 = inv2 + b * 6;
    const float* mk = masks + (size_t)j * NPIX;

    // outer sample position in intermediate pixel space
    float X = (2.0f * (float)x + 1.0f) / 512.0f - 1.0f;
    float Y = (2.0f * (float)y + 1.0f) / 512.0f - 1.0f;
    float gx = t1[0] * X + t1[1] * Y + t1[2];
    float gy = t1[3] * X + t1[4] * Y + t1[5];
    float sx = ((gx + 1.0f) * 512.0f - 1.0f) * 0.5f;
    float sy = ((gy + 1.0f) * 512.0f - 1.0f) * 0.5f;
    float xf = floorf(sx), yf = floorf(sy);
    int ix = (int)xf, iy = (int)yf;
    float wx = sx - xf, wy = sy - yf;

    // conservative inner-tap bounding box in mask texel space.
    // inner pos for integer inter coords (c,r): px = A0*c + A1*r + Kx, py = A3*c + A4*r + Ky
    float A0 = t2[0], A1 = t2[1], A3 = t2[3], A4 = t2[4];
    float Kx = 0.5f * (-511.0f * (A0 + A1) + 512.0f * t2[2] + 511.0f);
    float Ky = 0.5f * (-511.0f * (A3 + A4) + 512.0f * t2[5] + 511.0f);
    float px0 = A0 * (float)ix + A1 * (float)iy + Kx;
    float py0 = A3 * (float)ix + A4 * (float)iy + Ky;
    float pxmin = px0 + fminf(A0, 0.0f) + fminf(A1, 0.0f);
    float pxmax = px0 + fmaxf(A0, 0.0f) + fmaxf(A1, 0.0f);
    float pymin = py0 + fminf(A3, 0.0f) + fminf(A4, 0.0f);
    float pymax = py0 + fmaxf(A3, 0.0f) + fmaxf(A4, 0.0f);
    int xlo = max((int)floorf(pxmin) - 1, 0), xhi = min((int)floorf(pxmax) + 2, 511);
    int ylo = max((int)floorf(pymin) - 1, 0), yhi = min((int)floorf(pymax) + 2, 511);

    bool any = false;
    for (int tr = (ylo >> 4); tr <= (yhi >> 4); ++tr)
        for (int tc = (xlo >> 4); tc <= (xhi >> 4); ++tc)
            any = any || (((socc[tr] >> tc) & 1u) != 0u);
    if (xlo > xhi || ylo > yhi) any = false;

    float res = 0.0f;
    if (any) {
        float v = 0.0f;
        bool vx0 = (ix >= 0) && (ix < 512);
        bool vx1 = (ix >= -1) && (ix < 511);
        bool vy0 = (iy >= 0) && (iy < 512);
        bool vy1 = (iy >= -1) && (iy < 511);
        if (vx0 && vy0) v += rm2_val(mk, t2, ix,     iy    ) * ((1.0f - wx) * (1.0f - wy));
        if (vx1 && vy0) v += rm2_val(mk, t2, ix + 1, iy    ) * (wx * (1.0f - wy));
        if (vx0 && vy1) v += rm2_val(mk, t2, ix,     iy + 1) * ((1.0f - wx) * wy);
        if (vx1 && vy1) v += rm2_val(mk, t2, ix + 1, iy + 1) * (wx * wy);
        if (v >= 0.5f) {
            res = 1.0f;
            atomicMin(&sbb[0], y); atomicMin(&sbb[1], x);
            atomicMax(&sbb[2], y); atomicMax(&sbb[3], x);
        }
    }
    out3[(size_t)jb * NPIX + p] = res;

    __syncthreads();
    if (threadIdx.x == 0 && sbb[2] != INT_MIN) {
        atomicMin(&bbox[jb * 4 + 0], sbb[0]);
        atomicMin(&bbox[jb * 4 + 1], sbb[1]);
        atomicMax(&bbox[jb * 4 + 2], sbb[2]);
        atomicMax(&bbox[jb * 4 + 3], sbb[3]);
    }
}

// COM pass 1: one block per (j,b), scan bbox only -> threshold [f64, fixed-order reduce]
__global__ void __launch_bounds__(256) k_stats1(const float* __restrict__ pred,
                                                const float* __restrict__ mrot,
                                                const int* __restrict__ bbox,
                                                double* __restrict__ thr) {
    int jb = blockIdx.x;
    int b = jb & 15;
    int rmin = bbox[jb*4+0], cmin = bbox[jb*4+1], rmax = bbox[jb*4+2], cmax = bbox[jb*4+3];
    const float* img = pred + (size_t)b * NPIX;
    const float* mk  = mrot + (size_t)jb * NPIX;
    double msum = 0.0, isum = 0.0;
    if (rmax >= rmin) {
        int W = cmax - cmin + 1;
        int total = W * (rmax - rmin + 1);
        for (int i = threadIdx.x; i < total; i += 256) {
            int r = rmin + i / W, c = cmin + i % W;
            float m = mk[r * 512 + c];
            if (m != 0.0f) {
                msum += (double)m;
                isum += (double)(img[r * 512 + c] * m);
            }
        }
    }
    for (int o = 32; o > 0; o >>= 1) {
        msum += __shfl_down(msum, o, 64);
        isum += __shfl_down(isum, o, 64);
    }
    __shared__ double s0[4], s1[4];
    int lane = threadIdx.x & 63, w = threadIdx.x >> 6;
    if (lane == 0) { s0[w] = msum; s1[w] = isum; }
    __syncthreads();
    if (threadIdx.x == 0) {
        double M = s0[0] + s0[1] + s0[2] + s0[3];
        double I = s1[0] + s1[1] + s1[2] + s1[3];
        thr[jb] = (I / fmax(M, 1.0)) * 1.5;
    }
}

// COM pass 2: thresholded weighted centroid over bbox -> crop origin (dynamic_slice clamp)
__global__ void __launch_bounds__(256) k_stats2(const float* __restrict__ pred,
                                                const float* __restrict__ mrot,
                                                const int* __restrict__ bbox,
                                                const double* __restrict__ thr,
                                                int* __restrict__ xy) {
    int jb = blockIdx.x;
    int b = jb & 15;
    int rmin = bbox[jb*4+0], cmin = bbox[jb*4+1], rmax = bbox[jb*4+2], cmax = bbox[jb*4+3];
    double t = thr[jb];
    const float* img = pred + (size_t)b * NPIX;
    const float* mk  = mrot + (size_t)jb * NPIX;
    double wsum = 0.0, sy = 0.0, sx = 0.0;
    if (rmax >= rmin) {
        int W = cmax - cmin + 1;
        int total = W * (rmax - rmin + 1);
        for (int i = threadIdx.x; i < total; i += 256) {
            int r = rmin + i / W, c = cmin + i % W;
            float m = mk[r * 512 + c];
            if (m != 0.0f) {
                float v = img[r * 512 + c] * m;
                if ((double)v > t) {
                    double vd = (double)v;
                    wsum += vd;
                    sy += vd * (double)r;   // row (cx in reference)
                    sx += vd * (double)c;   // col (cy in reference)
                }
            }
        }
    }
    for (int o = 32; o > 0; o >>= 1) {
        wsum += __shfl_down(wsum, o, 64);
        sy   += __shfl_down(sy,   o, 64);
        sx   += __shfl_down(sx,   o, 64);
    }
    __shared__ double s0[4], s1[4], s2[4];
    int lane = threadIdx.x & 63, w = threadIdx.x >> 6;
    if (lane == 0) { s0[w] = wsum; s1[w] = sy; s2[w] = sx; }
    __syncthreads();
    if (threadIdx.x == 0) {
        double W_ = s0[0] + s0[1] + s0[2] + s0[3];
        double SY = s1[0] + s1[1] + s1[2] + s1[3];
        double SX = s2[0] + s2[1] + s2[2] + s2[3];
        double tot = W_ + 1e-8;
        int x0 = (int)rint(SY / tot) - RAD;
        int y0 = (int)rint(SX / tot) - RAD;
        x0 = min(max(x0, 0), 512 - DSZ);
        y0 = min(max(y0, 0), 512 - DSZ);
        xy[jb * 2 + 0] = x0;
        xy[jb * 2 + 1] = y0;
    }
}

// revise one mask index j across the batch: crop->dot divide->grid_sample->write back
__global__ void __launch_bounds__(256) k_patch(float* __restrict__ img,
                                               const int* __restrict__ xy,
                                               const float* __restrict__ inv1,
                                               const float* __restrict__ adj, int j) {
    __shared__ float patch[DSZ * DSZ];
    int b = blockIdx.x;
    int jb = j * 16 + b;
    int x0 = xy[jb * 2 + 0];   // row start
    int y0 = xy[jb * 2 + 1];   // col start
    float a = adj[b];
    float* im = img + (size_t)b * NPIX;
    for (int t = threadIdx.x; t < DSZ * DSZ; t += 256) {
        int u = t / DSZ, v = t % DSZ;
        float val = im[(x0 + u) * 512 + (y0 + v)];
        int du = u - RAD, dv = v - RAD;
        if (du * du + dv * dv <= 16) val = val / a;
        patch[t] = val;
    }
    __syncthreads();
    const float* th = inv1 + b * 6;
    float t0 = th[0], t1 = th[1], t2 = th[2], t3 = th[3], t4 = th[4], t5 = th[5];
    for (int t = threadIdx.x; t < DSZ * DSZ; t += 256) {
        int py = t / DSZ, px = t % DSZ;
        float X = (2.0f * (float)px + 1.0f) / 120.0f - 1.0f;
        float Y = (2.0f * (float)py + 1.0f) / 120.0f - 1.0f;
        float gx = t0 * X + t1 * Y + t2;
        float gy = t3 * X + t4 * Y + t5;
        float o = gs_bilinear(patch, DSZ, DSZ, gx, gy);
        im[(x0 + py) * 512 + (y0 + px)] = o;
    }
}

// ---------------- launcher ----------------

extern "C" void kernel_launch(void* const* d_in, const int* in_sizes, int n_in,
                              void* d_out, int out_size, void* d_ws, size_t ws_size,
                              hipStream_t stream) {
    const float* base  = (const float*)d_in[0];
    const float* sc    = (const float*)d_in[1];
    const float* rot   = (const float*)d_in[2];
    const float* tr    = (const float*)d_in[3];
    const float* adj   = (const float*)d_in[4];
    const float* masks = (const float*)d_in[5];

    float* out  = (float*)d_out;
    float* out0 = out;                               // base_inp
    float* out1 = out0 + (size_t)NB * NPIX;          // pred_input
    float* out2 = out1 + (size_t)NB * NPIX;          // pred_revise
    float* out3 = out2 + (size_t)NB * NPIX;          // masks_rot (4,16,512,512)

    // ws layout (bytes): inv @0 (1152B), thr @2048 (512B), xy @4096 (512B),
    //                    bbox @8192 (1KB), occ @12288 (512B)
    float*    inv1 = (float*)d_ws;
    float*    inv2 = inv1 + 96;
    float*    inv3 = inv1 + 192;
    double*   thr  = (double*)((char*)d_ws + 2048);
    int*      xy   = (int*)((char*)d_ws + 4096);
    int*      bbox = (int*)((char*)d_ws + 8192);
    unsigned* occ  = (unsigned*)((char*)d_ws + 12288);

    dim3 gridImg(NPIX / 256, NB);

    k_prep<<<1, 256, 0, stream>>>(sc, rot, tr, (float*)d_ws, bbox, occ);
    k_occ<<<4096, 64, 0, stream>>>(masks, occ);
    k_upsample<<<gridImg, 256, 0, stream>>>(base, out0);

    // image chain: base_inp -g3-> tmpA(out2) -g2-> tmpB(out3[:16]) -g1-> out1 (+out2 copy)
    k_gsample<<<gridImg, 256, 0, stream>>>(out0, out2, nullptr, inv3);
    k_gsample<<<gridImg, 256, 0, stream>>>(out2, out3, nullptr, inv2);
    k_gsample<<<gridImg, 256, 0, stream>>>(out3, out1, out2, inv1);  // dual store

    // masks (overwrites the tmp regions with final data)
    k_mask_chain<<<dim3(NPIX / 256, 64), 256, 0, stream>>>(masks, out3, inv1, inv2, occ, bbox);

    // COM stats over per-(j,b) bounding boxes
    k_stats1<<<64, 256, 0, stream>>>(out1, out3, bbox, thr);
    k_stats2<<<64, 256, 0, stream>>>(out1, out3, bbox, thr, xy);

    // sequential over j: matches reference update order (patches may overlap across j)
    for (int j = 0; j < 4; ++j)
        k_patch<<<NB, 256, 0, stream>>>(out2, xy, inv1, adj, j);
}

// Round 4
// 404.505 us; speedup vs baseline: 2.7048x; 1.0337x over previous
//
#include <hip/hip_runtime.h>
#include <math.h>
#include <limits.h>

#define NPIX (512*512)
#define NB 16
#define RAD 60
#define DSZ 120

// ---------------- device helpers ----------------

// torch/jax grid_sample semantics: bilinear, zero padding, align_corners=False
__device__ __forceinline__ float gs_bilinear(const float* img, int H, int W,
                                             float gx, float gy) {
    float x = ((gx + 1.0f) * (float)W - 1.0f) * 0.5f;
    float y = ((gy + 1.0f) * (float)H - 1.0f) * 0.5f;
    float xf = floorf(x), yf = floorf(y);
    int ix = (int)xf, iy = (int)yf;
    float wx = x - xf, wy = y - yf;
    float v = 0.0f;
    bool vx0 = (ix >= 0) && (ix < W);
    bool vx1 = (ix >= -1) && (ix < W - 1);
    bool vy0 = (iy >= 0) && (iy < H);
    bool vy1 = (iy >= -1) && (iy < H - 1);
    if (vx0 && vy0) v += img[iy*W + ix]         * ((1.0f - wx) * (1.0f - wy));
    if (vx1 && vy0) v += img[iy*W + ix + 1]     * (wx * (1.0f - wy));
    if (vx0 && vy1) v += img[(iy+1)*W + ix]     * ((1.0f - wx) * wy);
    if (vx1 && vy1) v += img[(iy+1)*W + ix + 1] * (wx * wy);
    return v;
}

// ---------------- kernels ----------------

// inverses + per-call ws init (bbox sentinels, occupancy bitmap zeros)
__global__ void k_prep(const float* __restrict__ sc, const float* __restrict__ rot,
                       const float* __restrict__ tr, float* __restrict__ ws_inv,
                       int* __restrict__ bbox, unsigned* __restrict__ occ) {
    int t = threadIdx.x;
    if (t < 48) {
        int m = t >> 4, b = t & 15;
        const float* th = (m == 0 ? sc : (m == 1 ? rot : tr)) + b * 6;
        float a  = th[0], bb = th[1], tx = th[2];
        float c  = th[3], d  = th[4], ty = th[5];
        float L10 = c / a;
        float dp  = d  - L10 * bb;
        float typ = ty - L10 * tx;
        float i10 = (0.0f - L10) / dp;
        float i00 = (1.0f - bb * i10) / a;
        float i11 = 1.0f / dp;
        float i01 = (0.0f - bb * i11) / a;
        float i12 = (0.0f - typ) / dp;
        float i02 = (0.0f - bb * i12 - tx) / a;
        float* o = ws_inv + m * 96 + b * 6;
        o[0] = i00; o[1] = i01; o[2] = i02;
        o[3] = i10; o[4] = i11; o[5] = i12;
    }
    // bbox[jb*4 + {0:rmin,1:cmin,2:rmax,3:cmax}]
    bbox[t] = ((t & 3) < 2) ? INT_MAX : INT_MIN;
    if (t < 128) occ[t] = 0u;
}

// mask-space occupancy: 1 bit per 16x16 tile per mask (word=tilerow, bit=tilecol)
__global__ void k_occ(const float* __restrict__ masks, unsigned* __restrict__ occ) {
    int tile = blockIdx.x;          // 0..4095
    int j = tile >> 10, t = tile & 1023;
    int ty = t >> 5, tx = t & 31;
    const float* mk = masks + (size_t)j * NPIX;
    int any = 0;
    for (int i = threadIdx.x; i < 256; i += 64) {
        int py = ty * 16 + (i >> 4), px = tx * 16 + (i & 15);
        if (mk[py * 512 + px] != 0.0f) any = 1;
    }
    unsigned long long m = __ballot(any);
    if (threadIdx.x == 0 && m) atomicOr(&occ[j * 32 + ty], 1u << tx);
}

// classify each (jb, output 16x16 tile): can it possibly touch a nonzero mask texel?
// Conservative: corner-exact linear bboxes + 1-texel rounding pad at each stage.
__global__ void __launch_bounds__(256) k_otile(const unsigned* __restrict__ occ,
                                               const float* __restrict__ inv1,
                                               const float* __restrict__ inv2,
                                               unsigned char* __restrict__ otile) {
    int idx = blockIdx.x * 256 + threadIdx.x;   // 0..65535
    int jb = idx >> 10, tile = idx & 1023;
    int j = jb >> 4, b = jb & 15;
    int ty = tile >> 5, tx = tile & 31;
    const float* t1 = inv1 + b * 6;
    const float* t2 = inv2 + b * 6;
    float xs[2] = { (float)(tx * 16), (float)(tx * 16 + 15) };
    float ys[2] = { (float)(ty * 16), (float)(ty * 16 + 15) };
    float sxmin = 1e30f, sxmax = -1e30f, symin = 1e30f, symax = -1e30f;
    for (int cy = 0; cy < 2; ++cy)
        for (int cx = 0; cx < 2; ++cx) {
            float X = (2.0f * xs[cx] + 1.0f) / 512.0f - 1.0f;
            float Y = (2.0f * ys[cy] + 1.0f) / 512.0f - 1.0f;
            float gx = t1[0] * X + t1[1] * Y + t1[2];
            float gy = t1[3] * X + t1[4] * Y + t1[5];
            float sx = ((gx + 1.0f) * 512.0f - 1.0f) * 0.5f;
            float sy = ((gy + 1.0f) * 512.0f - 1.0f) * 0.5f;
            sxmin = fminf(sxmin, sx); sxmax = fmaxf(sxmax, sx);
            symin = fminf(symin, sy); symax = fmaxf(symax, sy);
        }
    // intermediate-space integer tap coords (pad 1 for float rounding)
    int c0 = max((int)floorf(sxmin) - 1, 0), c1 = min((int)floorf(sxmax) + 2, 511);
    int r0 = max((int)floorf(symin) - 1, 0), r1 = min((int)floorf(symax) + 2, 511);
    unsigned char any = 0;
    if (c0 <= c1 && r0 <= r1) {
        float A0 = t2[0], A1 = t2[1], A3 = t2[3], A4 = t2[4];
        float Kx = 0.5f * (-511.0f * (A0 + A1) + 512.0f * t2[2] + 511.0f);
        float Ky = 0.5f * (-511.0f * (A3 + A4) + 512.0f * t2[5] + 511.0f);
        float pxmin = A0 * (A0 >= 0.f ? c0 : c1) + A1 * (A1 >= 0.f ? r0 : r1) + Kx;
        float pxmax = A0 * (A0 >= 0.f ? c1 : c0) + A1 * (A1 >= 0.f ? r1 : r0) + Kx;
        float pymin = A3 * (A3 >= 0.f ? c0 : c1) + A4 * (A4 >= 0.f ? r0 : r1) + Ky;
        float pymax = A3 * (A3 >= 0.f ? c1 : c0) + A4 * (A4 >= 0.f ? r1 : r0) + Ky;
        int xlo = max((int)floorf(pxmin) - 1, 0), xhi = min((int)floorf(pxmax) + 2, 511);
        int ylo = max((int)floorf(pymin) - 1, 0), yhi = min((int)floorf(pymax) + 2, 511);
        if (xlo <= xhi && ylo <= yhi)
            for (int tr = ylo >> 4; tr <= yhi >> 4; ++tr)
                for (int tc = xlo >> 4; tc <= xhi >> 4; ++tc)
                    if ((occ[j * 32 + tr] >> tc) & 1u) any = 1;
    }
    otile[jb * 1024 + tile] = any;
}

// jax.image.resize linear 128->512
__global__ void __launch_bounds__(256) k_upsample(const float* __restrict__ in,
                                                  float* __restrict__ out) {
    int b = blockIdx.y;
    int p = blockIdx.x * 256 + threadIdx.x;
    int y = p >> 9, x = p & 511;
    const float* src = in + b * 128 * 128;
    float sx = (float)x * 0.25f - 0.375f;
    float sy = (float)y * 0.25f - 0.375f;
    float fx0 = floorf(sx), fy0 = floorf(sy);
    int ix = (int)fx0, iy = (int)fy0;
    float fx = sx - fx0, fy = sy - fy0;
    int ix0 = min(max(ix, 0), 127),     ix1 = min(max(ix + 1, 0), 127);
    int iy0 = min(max(iy, 0), 127),     iy1 = min(max(iy + 1, 0), 127);
    float v00 = src[iy0 * 128 + ix0], v10 = src[iy0 * 128 + ix1];
    float v01 = src[iy1 * 128 + ix0], v11 = src[iy1 * 128 + ix1];
    float v = (v00 * (1.0f - fx) + v10 * fx) * (1.0f - fy)
            + (v01 * (1.0f - fx) + v11 * fx) * fy;
    out[(size_t)b * NPIX + p] = v;
}

// one affine grid_sample pass over (B,512,512); optional dual store
__global__ void __launch_bounds__(256) k_gsample(const float* __restrict__ src,
                                                 float* __restrict__ dst,
                                                 float* __restrict__ dst2,
                                                 const float* __restrict__ thetas) {
    int b = blockIdx.y;
    int p = blockIdx.x * 256 + threadIdx.x;
    int y = p >> 9, x = p & 511;
    const float* th = thetas + b * 6;
    float X = (2.0f * (float)x + 1.0f) / 512.0f - 1.0f;
    float Y = (2.0f * (float)y + 1.0f) / 512.0f - 1.0f;
    float gx = th[0] * X + th[1] * Y + th[2];
    float gy = th[3] * X + th[4] * Y + th[5];
    float v = gs_bilinear(src + (size_t)b * NPIX, 512, 512, gx, gy);
    dst[(size_t)b * NPIX + p] = v;
    if (dst2) dst2[(size_t)b * NPIX + p] = v;
}

__device__ __forceinline__ float rm2_val(const float* mk, const float* t2, int cx_, int ry_) {
    float X2 = (2.0f * (float)cx_ + 1.0f) / 512.0f - 1.0f;
    float Y2 = (2.0f * (float)ry_ + 1.0f) / 512.0f - 1.0f;
    float g2x = t2[0] * X2 + t2[1] * Y2 + t2[2];
    float g2y = t2[3] * X2 + t2[4] * Y2 + t2[5];
    return gs_bilinear(mk, 512, 512, g2x, g2y);
}

// fused: rm = gs(gs(mask_j, g2), g1) >= 0.5; tile-level skip; set-pixel bbox tracking.
// grid: (1024 tiles, 64 jb), block = one 16x16 output tile.
__global__ void __launch_bounds__(256) k_mask_chain(const float* __restrict__ masks,
                                                    float* __restrict__ out3,
                                                    const float* __restrict__ inv1,
                                                    const float* __restrict__ inv2,
                                                    const unsigned char* __restrict__ otile,
                                                    int* __restrict__ bbox) {
    int jb = blockIdx.y;
    int tile = blockIdx.x;
    int ty = tile >> 5, tx = tile & 31;
    int y = ty * 16 + (threadIdx.x >> 4);
    int x = tx * 16 + (threadIdx.x & 15);
    size_t op = (size_t)jb * NPIX + y * 512 + x;

    if (!otile[jb * 1024 + tile]) {     // block-uniform: provably all-zero tile
        out3[op] = 0.0f;
        return;
    }

    __shared__ int sbb[4];
    if (threadIdx.x == 0) { sbb[0] = INT_MAX; sbb[1] = INT_MAX; sbb[2] = INT_MIN; sbb[3] = INT_MIN; }
    __syncthreads();

    int j = jb >> 4, b = jb & 15;
    const float* t1 = inv1 + b * 6;
    const float* t2 = inv2 + b * 6;
    const float* mk = masks + (size_t)j * NPIX;

    float X = (2.0f * (float)x + 1.0f) / 512.0f - 1.0f;
    float Y = (2.0f * (float)y + 1.0f) / 512.0f - 1.0f;
    float gx = t1[0] * X + t1[1] * Y + t1[2];
    float gy = t1[3] * X + t1[4] * Y + t1[5];
    float sx = ((gx + 1.0f) * 512.0f - 1.0f) * 0.5f;
    float sy = ((gy + 1.0f) * 512.0f - 1.0f) * 0.5f;
    float xf = floorf(sx), yf = floorf(sy);
    int ix = (int)xf, iy = (int)yf;
    float wx = sx - xf, wy = sy - yf;

    float v = 0.0f;
    bool vx0 = (ix >= 0) && (ix < 512);
    bool vx1 = (ix >= -1) && (ix < 511);
    bool vy0 = (iy >= 0) && (iy < 512);
    bool vy1 = (iy >= -1) && (iy < 511);
    if (vx0 && vy0) v += rm2_val(mk, t2, ix,     iy    ) * ((1.0f - wx) * (1.0f - wy));
    if (vx1 && vy0) v += rm2_val(mk, t2, ix + 1, iy    ) * (wx * (1.0f - wy));
    if (vx0 && vy1) v += rm2_val(mk, t2, ix,     iy + 1) * ((1.0f - wx) * wy);
    if (vx1 && vy1) v += rm2_val(mk, t2, ix + 1, iy + 1) * (wx * wy);

    float res = 0.0f;
    if (v >= 0.5f) {
        res = 1.0f;
        atomicMin(&sbb[0], y); atomicMin(&sbb[1], x);
        atomicMax(&sbb[2], y); atomicMax(&sbb[3], x);
    }
    out3[op] = res;

    __syncthreads();
    if (threadIdx.x == 0 && sbb[2] != INT_MIN) {
        atomicMin(&bbox[jb * 4 + 0], sbb[0]);
        atomicMin(&bbox[jb * 4 + 1], sbb[1]);
        atomicMax(&bbox[jb * 4 + 2], sbb[2]);
        atomicMax(&bbox[jb * 4 + 3], sbb[3]);
    }
}

// fused COM stats: one block per (j,b); phase A -> threshold (LDS), phase B -> crop origin
__global__ void __launch_bounds__(256) k_stats(const float* __restrict__ pred,
                                               const float* __restrict__ mrot,
                                               const int* __restrict__ bbox,
                                               int* __restrict__ xy) {
    int jb = blockIdx.x;
    int b = jb & 15;
    int rmin = bbox[jb*4+0], cmin = bbox[jb*4+1], rmax = bbox[jb*4+2], cmax = bbox[jb*4+3];
    const float* img = pred + (size_t)b * NPIX;
    const float* mk  = mrot + (size_t)jb * NPIX;
    int lane = threadIdx.x & 63, w = threadIdx.x >> 6;
    int W = cmax - cmin + 1;
    int total = (rmax >= rmin) ? W * (rmax - rmin + 1) : 0;

    // phase A: sum(mask), sum(img*mask)
    double msum = 0.0, isum = 0.0;
    for (int i = threadIdx.x; i < total; i += 256) {
        int r = rmin + i / W, c = cmin + i % W;
        float m = mk[r * 512 + c];
        if (m != 0.0f) {
            msum += (double)m;
            isum += (double)(img[r * 512 + c] * m);
        }
    }
    for (int o = 32; o > 0; o >>= 1) {
        msum += __shfl_down(msum, o, 64);
        isum += __shfl_down(isum, o, 64);
    }
    __shared__ double s0[4], s1[4], s2[4];
    __shared__ double sthr;
    if (lane == 0) { s0[w] = msum; s1[w] = isum; }
    __syncthreads();
    if (threadIdx.x == 0) {
        double M = s0[0] + s0[1] + s0[2] + s0[3];
        double I = s1[0] + s1[1] + s1[2] + s1[3];
        sthr = (I / fmax(M, 1.0)) * 1.5;
    }
    __syncthreads();
    double t = sthr;

    // phase B: thresholded weighted centroid
    double wsum = 0.0, sy = 0.0, sx = 0.0;
    for (int i = threadIdx.x; i < total; i += 256) {
        int r = rmin + i / W, c = cmin + i % W;
        float m = mk[r * 512 + c];
        if (m != 0.0f) {
            float v = img[r * 512 + c] * m;
            if ((double)v > t) {
                double vd = (double)v;
                wsum += vd;
                sy += vd * (double)r;   // row (cx in reference)
                sx += vd * (double)c;   // col (cy in reference)
            }
        }
    }
    for (int o = 32; o > 0; o >>= 1) {
        wsum += __shfl_down(wsum, o, 64);
        sy   += __shfl_down(sy,   o, 64);
        sx   += __shfl_down(sx,   o, 64);
    }
    __syncthreads();
    if (lane == 0) { s0[w] = wsum; s1[w] = sy; s2[w] = sx; }
    __syncthreads();
    if (threadIdx.x == 0) {
        double W_ = s0[0] + s0[1] + s0[2] + s0[3];
        double SY = s1[0] + s1[1] + s1[2] + s1[3];
        double SX = s2[0] + s2[1] + s2[2] + s2[3];
        double tot = W_ + 1e-8;
        int x0 = (int)rint(SY / tot) - RAD;
        int y0 = (int)rint(SX / tot) - RAD;
        x0 = min(max(x0, 0), 512 - DSZ);
        y0 = min(max(y0, 0), 512 - DSZ);
        xy[jb * 2 + 0] = x0;
        xy[jb * 2 + 1] = y0;
    }
}

// revise one mask index j across the batch: crop->dot divide->grid_sample->write back
__global__ void __launch_bounds__(256) k_patch(float* __restrict__ img,
                                               const int* __restrict__ xy,
                                               const float* __restrict__ inv1,
                                               const float* __restrict__ adj, int j) {
    __shared__ float patch[DSZ * DSZ];
    int b = blockIdx.x;
    int jb = j * 16 + b;
    int x0 = xy[jb * 2 + 0];   // row start
    int y0 = xy[jb * 2 + 1];   // col start
    float a = adj[b];
    float* im = img + (size_t)b * NPIX;
    for (int t = threadIdx.x; t < DSZ * DSZ; t += 256) {
        int u = t / DSZ, v = t % DSZ;
        float val = im[(x0 + u) * 512 + (y0 + v)];
        int du = u - RAD, dv = v - RAD;
        if (du * du + dv * dv <= 16) val = val / a;
        patch[t] = val;
    }
    __syncthreads();
    const float* th = inv1 + b * 6;
    float t0 = th[0], t1 = th[1], t2 = th[2], t3 = th[3], t4 = th[4], t5 = th[5];
    for (int t = threadIdx.x; t < DSZ * DSZ; t += 256) {
        int py = t / DSZ, px = t % DSZ;
        float X = (2.0f * (float)px + 1.0f) / 120.0f - 1.0f;
        float Y = (2.0f * (float)py + 1.0f) / 120.0f - 1.0f;
        float gx = t0 * X + t1 * Y + t2;
        float gy = t3 * X + t4 * Y + t5;
        float o = gs_bilinear(patch, DSZ, DSZ, gx, gy);
        im[(x0 + py) * 512 + (y0 + px)] = o;
    }
}

// ---------------- launcher ----------------

extern "C" void kernel_launch(void* const* d_in, const int* in_sizes, int n_in,
                              void* d_out, int out_size, void* d_ws, size_t ws_size,
                              hipStream_t stream) {
    const float* base  = (const float*)d_in[0];
    const float* sc    = (const float*)d_in[1];
    const float* rot   = (const float*)d_in[2];
    const float* tr    = (const float*)d_in[3];
    const float* adj   = (const float*)d_in[4];
    const float* masks = (const float*)d_in[5];

    float* out  = (float*)d_out;
    float* out0 = out;                               // base_inp
    float* out1 = out0 + (size_t)NB * NPIX;          // pred_input
    float* out2 = out1 + (size_t)NB * NPIX;          // pred_revise
    float* out3 = out2 + (size_t)NB * NPIX;          // masks_rot (4,16,512,512)

    // ws layout (bytes): inv @0, xy @4096, bbox @8192, occ @12288, otile @16384 (64KB)
    float*         inv1  = (float*)d_ws;
    float*         inv2  = inv1 + 96;
    float*         inv3  = inv1 + 192;
    int*           xy    = (int*)((char*)d_ws + 4096);
    int*           bbox  = (int*)((char*)d_ws + 8192);
    unsigned*      occ   = (unsigned*)((char*)d_ws + 12288);
    unsigned char* otile = (unsigned char*)((char*)d_ws + 16384);

    dim3 gridImg(NPIX / 256, NB);

    k_prep<<<1, 256, 0, stream>>>(sc, rot, tr, (float*)d_ws, bbox, occ);
    k_occ<<<4096, 64, 0, stream>>>(masks, occ);
    k_otile<<<256, 256, 0, stream>>>(occ, inv1, inv2, otile);
    k_upsample<<<gridImg, 256, 0, stream>>>(base, out0);

    // image chain: base_inp -g3-> tmpA(out2) -g2-> tmpB(out3[:16]) -g1-> out1 (+out2 copy)
    k_gsample<<<gridImg, 256, 0, stream>>>(out0, out2, nullptr, inv3);
    k_gsample<<<gridImg, 256, 0, stream>>>(out2, out3, nullptr, inv2);
    k_gsample<<<gridImg, 256, 0, stream>>>(out3, out1, out2, inv1);  // dual store

    // masks (overwrites the tmp regions with final data)
    k_mask_chain<<<dim3(1024, 64), 256, 0, stream>>>(masks, out3, inv1, inv2, otile, bbox);

    // fused COM stats over per-(j,b) bounding boxes
    k_stats<<<64, 256, 0, stream>>>(out1, out3, bbox, xy);

    // sequential over j: matches reference update order (patches may overlap across j)
    for (int j = 0; j < 4; ++j)
        k_patch<<<NB, 256, 0, stream>>>(out2, xy, inv1, adj, j);
}